// Round 6
// baseline (382.107 us; speedup 1.0000x reference)
//
#include <hip/hip_runtime.h>
#include <cstdint>
#include <cmath>

typedef unsigned short u16;
typedef u16   u16x4  __attribute__((ext_vector_type(4)));
typedef u16   u16x8  __attribute__((ext_vector_type(8)));
typedef __bf16 bf16x8 __attribute__((ext_vector_type(8)));
typedef float f32x4  __attribute__((ext_vector_type(4)));

__device__ __forceinline__ u16 f2bf(float f) {
    uint32_t u = __builtin_bit_cast(uint32_t, f);
    u += 0x7fffu + ((u >> 16) & 1u);   // round-to-nearest-even
    return (u16)(u >> 16);
}
__device__ __forceinline__ float bf2f(u16 v) {
    uint32_t u = ((uint32_t)v) << 16;
    return __builtin_bit_cast(float, u);
}
// async global->LDS, 16B per lane. LDS dest is wave-uniform base + lane*16.
__device__ __forceinline__ void gload_lds16(const u16* g, u16* l) {
    __builtin_amdgcn_global_load_lds((const __attribute__((address_space(1))) void*)g,
                                     (__attribute__((address_space(3))) void*)l,
                                     16, 0, 0);
}

// ---- prep: cast X fp32->bf16  +  transpose-cast W -> Wt[N][K] bf16  +  zero pv flags ----
__global__ __launch_bounds__(256) void prep_kernel(const float* __restrict__ X,
                                                   const float* __restrict__ Wq,
                                                   const float* __restrict__ Wk,
                                                   const float* __restrict__ Wv,
                                                   u16* __restrict__ Xb,
                                                   u16* __restrict__ Wt,
                                                   int* __restrict__ Flags) {
    __shared__ u16 tile[64 * 72];
    typedef float f4 __attribute__((ext_vector_type(4)));
    const int bid = blockIdx.x;
    if (bid < 8192) {                       // cast X: 8192 blocks * 256 thr * 4 elems
        const int idx = bid * 256 + threadIdx.x;
        f4 f = ((const f4*)X)[idx];
        u16x4 o;
        o[0] = f2bf(f[0]); o[1] = f2bf(f[1]); o[2] = f2bf(f[2]); o[3] = f2bf(f[3]);
        ((u16x4*)Xb)[idx] = o;
        return;
    }
    if (bid == 8960) {                      // zero the 256 split-K flags (ws is 0xAA-poisoned)
        Flags[threadIdx.x] = 0;
        return;
    }
    const int id = bid - 8192;              // 768 blocks: W transpose-cast
    const int z = id >> 8, rem = id & 255;
    const float* W = (z == 0) ? Wq : (z == 1) ? Wk : Wv;
    u16* out = Wt + ((size_t)z << 20);
    const int nt = (rem & 15) * 64, kt = (rem >> 4) * 64;
    const int t = threadIdx.x, r = t >> 2, cq = (t & 3) * 16;
    const float* src = W + (size_t)(kt + r) * 1024 + nt + cq;
#pragma unroll
    for (int q = 0; q < 4; q++) {
        f4 f = ((const f4*)src)[q];
        tile[r * 72 + cq + q * 4 + 0] = f2bf(f[0]);
        tile[r * 72 + cq + q * 4 + 1] = f2bf(f[1]);
        tile[r * 72 + cq + q * 4 + 2] = f2bf(f[2]);
        tile[r * 72 + cq + q * 4 + 3] = f2bf(f[3]);
    }
    __syncthreads();
    u16x8 o0, o1;
#pragma unroll
    for (int e = 0; e < 8; e++) { o0[e] = tile[(cq + e) * 72 + r]; o1[e] = tile[(cq + 8 + e) * 72 + r]; }
    u16* dst = out + (size_t)(nt + r) * 1024 + kt + cq;
    *(u16x8*)dst = o0;
    *(u16x8*)(dst + 8) = o1;
}

// ------------- shared GEMM core: C[M,N] (+)= A[M,K_rng] * Bt[N,K_rng]^T -------------
// 128x128 tile, BK=32, 256 threads = 4 waves (2x2), 4x4 16x16x32 MFMA tiles/wave.
// OUTMODE: 0 = bf16 store, 1 = f32 store. Output tile origin (om0,on0) decoupled
// from input origin (m0,n0) so partial tiles can be written to compact buffers.
template <int OUTMODE>
__device__ __forceinline__ void gemm_bt_core(u16* __restrict__ smem,
                                             const u16* __restrict__ A,
                                             const u16* __restrict__ Bt,
                                             void* __restrict__ outp,
                                             const int ldk, const int ldo,
                                             const int kbeg, const int kend,
                                             const int m0, const int n0,
                                             const int om0, const int on0) {
    u16* As = smem;            // [128][32]
    u16* Bs = smem + 4096;     // [128][32]
    const int tid = (int)threadIdx.x;
    const int wave = tid >> 6, lane = tid & 63;
    const int wm = wave >> 1, wn = wave & 1;

    f32x4 acc[4][4] = {};

    const int sr = lane >> 2;            // row within 16-row issue group
    const int sc = (lane & 3) * 8;       // col chunk (8 bf16 = 16B)
    const u16* gA = A  + (size_t)(m0 + wave * 32 + sr) * ldk + sc;
    const u16* gB = Bt + (size_t)(n0 + wave * 32 + sr) * ldk + sc;
    u16* lA = As + wave * 1024;          // wave-uniform LDS base
    u16* lB = Bs + wave * 1024;
    const size_t rstep = (size_t)ldk * 16;

    const u16* pa = As + (wm * 64 + (lane & 15)) * 32 + (lane >> 4) * 8;
    const u16* pb = Bs + (wn * 64 + (lane & 15)) * 32 + (lane >> 4) * 8;

    for (int k0 = kbeg; k0 < kend; k0 += 32) {
        gload_lds16(gA + k0,         lA);
        gload_lds16(gA + k0 + rstep, lA + 512);
        gload_lds16(gB + k0,         lB);
        gload_lds16(gB + k0 + rstep, lB + 512);
        __syncthreads();
        bf16x8 a[4], b[4];
#pragma unroll
        for (int i = 0; i < 4; i++) a[i] = *(const bf16x8*)(pa + i * 512);
#pragma unroll
        for (int j = 0; j < 4; j++) b[j] = *(const bf16x8*)(pb + j * 512);
#pragma unroll
        for (int i = 0; i < 4; i++)
#pragma unroll
            for (int j = 0; j < 4; j++)
                acc[i][j] = __builtin_amdgcn_mfma_f32_16x16x32_bf16(a[i], b[j], acc[i][j], 0, 0, 0);
        __syncthreads();
    }

    // epilogue: C/D layout col=lane&15, row=(lane>>4)*4+reg  [m89/m91-verified]
    const int row0 = om0 + wm * 64 + ((lane >> 4) << 2);
    const int col0 = on0 + wn * 64 + (lane & 15);
    if constexpr (OUTMODE == 0) {
        u16* o = (u16*)outp;
#pragma unroll
        for (int i = 0; i < 4; i++)
#pragma unroll
            for (int r = 0; r < 4; r++) {
                u16* po = o + (size_t)(row0 + i * 16 + r) * ldo + col0;
#pragma unroll
                for (int j = 0; j < 4; j++) po[j * 16] = f2bf(acc[i][j][r]);
            }
    } else {
        float* o = (float*)outp;
#pragma unroll
        for (int i = 0; i < 4; i++)
#pragma unroll
            for (int r = 0; r < 4; r++) {
                float* po = o + (size_t)(row0 + i * 16 + r) * ldo + col0;
#pragma unroll
                for (int j = 0; j < 4; j++) po[j * 16] = acc[i][j][r];
            }
    }
}

// QKV (one z per dispatch for profile visibility; measured split cost ~0):
// X[8192,1024] * Wt[z][1024,1024]^T -> QKV[z][8192,1024] bf16
__global__ __launch_bounds__(256) void qkv_gemm_kernel(const u16* __restrict__ Xb,
                                                       const u16* __restrict__ Wt,
                                                       u16* __restrict__ QKV, int z) {
    __shared__ u16 smem[8192];
    gemm_bt_core<0>(smem, Xb, Wt + ((size_t)z << 20), QKV + ((size_t)z << 23),
                    1024, 1024, 0, 1024, blockIdx.y * 128, blockIdx.x * 128,
                    blockIdx.y * 128, blockIdx.x * 128);
}

// fused: S = Q*K^T (544 causal tiles, compact triangular grid)  +  V transpose (2048 blocks).
// GEMM blocks dispatched first; transpose blocks backfill the scheduling tail.
__global__ __launch_bounds__(256) void s_tr_kernel(const u16* __restrict__ QKV,
                                                   u16* __restrict__ S,
                                                   u16* __restrict__ Vt) {
    __shared__ u16 smem[8192];
    const int bid = blockIdx.x;
    if (bid < 544) {
        const int b = bid / 136, t = bid - b * 136;
        int it = (int)((sqrtf(8.f * (float)t + 1.f) - 1.f) * 0.5f);
        while ((it + 1) * (it + 2) / 2 <= t) it++;
        while (it * (it + 1) / 2 > t) it--;
        const int jt = t - it * (it + 1) / 2;
        const u16* Q  = QKV + ((size_t)b << 21);
        const u16* Kp = QKV + ((size_t)1 << 23) + ((size_t)b << 21);
        gemm_bt_core<0>(smem, Q, Kp, S + ((size_t)b << 22), 1024, 2048, 0, 1024,
                        it * 128, jt * 128, it * 128, jt * 128);
        return;
    }
    // V[b][s][e] -> Vt[b][e][s], 64x64 tiles
    const int id = bid - 544;
    const int z = id >> 9, rem = id & 511;
    const u16* src = QKV + ((size_t)2 << 23) + ((size_t)z << 21);
    u16* dst = Vt + ((size_t)z << 21);
    const int st = (rem & 31) * 64, et = (rem >> 5) * 64;
    u16 (*tile)[72] = (u16(*)[72])smem;
    const int t = threadIdx.x, r = t >> 2, cq = (t & 3) * 16;
    const u16* p = src + (size_t)(st + r) * 1024 + et + cq;
    u16x8 u0 = *(const u16x8*)p;
    u16x8 u1 = *(const u16x8*)(p + 8);
#pragma unroll
    for (int e = 0; e < 8; e++) { tile[r][cq + e] = u0[e]; tile[r][cq + 8 + e] = u1[e]; }
    __syncthreads();
    u16x8 o0, o1;
#pragma unroll
    for (int e = 0; e < 8; e++) { o0[e] = tile[cq + e][r]; o1[e] = tile[cq + 8 + e][r]; }
    u16* q = dst + (size_t)(et + r) * 2048 + st + cq;
    *(u16x8*)q = o0;
    *(u16x8*)(q + 8) = o1;
}

// O = P * Vt^T. Deterministic 2-way split-K (tiles it>=8): both chunks write f32
// partials to a 2-slot Part buffer; the LAST-finishing chunk (per-tile device-scope
// atomic flag, rocPRIM look-back pattern: store -> threadfence -> sync -> atomicAdd)
// re-reads both partials and writes O. Whole tiles (it<8) store O directly.
// Replaces R5's 256-block latency-exposed reduce dispatch.
__global__ __launch_bounds__(256) void pv_gemm_kernel(const u16* __restrict__ P,
                                                      const u16* __restrict__ Vt,
                                                      float* __restrict__ O,
                                                      float* __restrict__ Part,
                                                      int* __restrict__ Flags) {
    __shared__ u16 smem[8192];
    __shared__ int amLast;
    // slot -> (it, kind): kind 0=whole, 1=c0 [0,h), 2=c1 [h,u); triples {c,c+256,c+512}
    // sum to 17 K128-units per CU under round-robin mapping.
    const unsigned char IT[24]   = {15,14, 7,14,13,13,12,12, 15, 6,11,11,10,10, 9, 5,  0, 1, 2, 8, 3, 9, 8, 4};
    const unsigned char KIND[24] = { 1, 1, 0, 2, 1, 2, 1, 2,  2, 0, 1, 2, 1, 2, 1, 0,  0, 0, 0, 2, 0, 2, 1, 0};
    const int j = blockIdx.x;                 // 0..767
    const int slot = j >> 5, combo = j & 31;
    const int it = IT[slot], kind = KIND[slot];
    const int b = combo >> 3, n0 = (combo & 7) * 128;
    const int u = it + 1, h = (u + 1) >> 1;
    if (kind == 0) {
        gemm_bt_core<1>(smem, P + ((size_t)b << 22), Vt + ((size_t)b << 21),
                        O + ((size_t)b << 21),
                        2048, 1024, 0, u * 128, it * 128, n0, it * 128, n0);
        return;
    }
    const int key = (it - 8) * 32 + combo;    // 0..255
    const int k_lo = (kind == 2) ? h * 128 : 0;
    const int k_hi = (kind == 1) ? h * 128 : u * 128;
    float* mine = Part + ((size_t)(key * 2 + (kind - 1)) << 14);   // 128x128 f32 tile
    gemm_bt_core<1>(smem, P + ((size_t)b << 22), Vt + ((size_t)b << 21), mine,
                    2048, 128, k_lo, k_hi, it * 128, n0, 0, 0);
    __threadfence();                          // make this thread's partial stores device-visible
    __syncthreads();                          // all threads stored+fenced
    if (threadIdx.x == 0) amLast = (atomicAdd(&Flags[key], 1) == 1);
    __syncthreads();
    if (amLast) {
        __threadfence();                      // acquire: see the other chunk's stores
        const f32x4* p0 = (const f32x4*)(Part + ((size_t)(key * 2) << 14));
        const f32x4* p1 = p0 + 4096;
        float* o = O + ((size_t)b << 21) + (size_t)(it * 128) * 1024 + n0;
        const int tid = threadIdx.x;
#pragma unroll
        for (int e = 0; e < 16; e++) {
            const int flat = e * 256 + tid;   // f32x4 index within 128x128 tile
            const int row = flat >> 5, col = (flat & 31) * 4;
            f32x4 a = p0[flat], c = p1[flat];
            a[0] += c[0]; a[1] += c[1]; a[2] += c[2]; a[3] += c[3];
            *(f32x4*)(o + (size_t)row * 1024 + col) = a;
        }
    }
}

// --------- in-place causal softmax (scale 1/32), truncated to kend=((i>>7)+1)*128 ---------
__global__ __launch_bounds__(256) void softmax_kernel(u16* __restrict__ S) {
    const int wave = threadIdx.x >> 6, lane = threadIdx.x & 63;
    const int g = blockIdx.x * 4 + wave;       // 0..8191
    const int b = g >> 11, i = g & 2047;
    u16* row = S + ((size_t)b << 22) + ((size_t)i << 11);
    const int n = i + 1;                        // valid keys
    const int kend = ((i >> 7) + 1) << 7;       // pv reads cols [0, kend)
    const int nt_ = (kend + 511) >> 9;          // active 512-col chunks (1..4), wave-uniform
    const float NEG = -1e30f;
    float v[32];
    float m = NEG;
#pragma unroll
    for (int t = 0; t < 4; t++) {
        if (t < nt_) {
            u16x8 u = *(const u16x8*)(row + t * 512 + lane * 8);
#pragma unroll
            for (int e = 0; e < 8; e++) {
                const int col = t * 512 + lane * 8 + e;
                float f = (col < n) ? bf2f(u[e]) : NEG;
                v[t * 8 + e] = f;
                m = fmaxf(m, f);
            }
        }
    }
#pragma unroll
    for (int off = 32; off > 0; off >>= 1) m = fmaxf(m, __shfl_xor(m, off, 64));
    const float sc = 0.03125f * 1.44269504088896f;   // (1/sqrt(1024)) * log2(e)
    float s = 0.f;
#pragma unroll
    for (int t = 0; t < 4; t++) {
        if (t < nt_) {
#pragma unroll
            for (int e = 0; e < 8; e++) {
                const float x = v[t * 8 + e];
                const float e2 = (x == NEG) ? 0.f : exp2f((x - m) * sc);
                v[t * 8 + e] = e2;
                s += e2;
            }
        }
    }
#pragma unroll
    for (int off = 32; off > 0; off >>= 1) s += __shfl_xor(s, off, 64);
    const float inv = 1.f / s;
#pragma unroll
    for (int t = 0; t < 4; t++) {
        if (t < nt_) {
            u16x8 o;
#pragma unroll
            for (int e = 0; e < 8; e++) o[e] = f2bf(v[t * 8 + e] * inv);
            *(u16x8*)(row + t * 512 + lane * 8) = o;
        }
    }
}

extern "C" void kernel_launch(void* const* d_in, const int* in_sizes, int n_in,
                              void* d_out, int out_size, void* d_ws, size_t ws_size,
                              hipStream_t stream) {
    const float* X  = (const float*)d_in[0];
    const float* Wq = (const float*)d_in[1];
    const float* Wk = (const float*)d_in[2];
    const float* Wv = (const float*)d_in[3];
    float* out = (float*)d_out;

    // ws layout (u16 elems): Xb 8M | Wt 3M | QKV 24M | S 16M | Flags -> ~102 MB + 1KB
    u16* ws  = (u16*)d_ws;
    u16* Xb  = ws;                                   // 1<<23 elems (reused as Vt)
    u16* Wt  = Xb + ((size_t)1 << 23);               // 3 * (1<<20)
    u16* QKV = Wt + 3 * ((size_t)1 << 20);           // 3 * (1<<23)
    u16* S   = QKV + 3 * ((size_t)1 << 23);          // 1<<24
    u16* Vt  = Xb;                                   // Xb dead after QKV GEMM
    float* Part = (float*)QKV;                       // Q+K regions (32 MB) dead during pv
    int* Flags  = (int*)(S + ((size_t)1 << 24));     // 256 ints

    prep_kernel<<<8961, 256, 0, stream>>>(X, Wq, Wk, Wv, Xb, Wt, Flags);
    qkv_gemm_kernel<<<dim3(8, 64), 256, 0, stream>>>(Xb, Wt, QKV, 0);
    qkv_gemm_kernel<<<dim3(8, 64), 256, 0, stream>>>(Xb, Wt, QKV, 1);
    qkv_gemm_kernel<<<dim3(8, 64), 256, 0, stream>>>(Xb, Wt, QKV, 2);
    s_tr_kernel<<<2592, 256, 0, stream>>>(QKV, S, Vt);
    softmax_kernel<<<2048, 256, 0, stream>>>(S);
    pv_gemm_kernel<<<768, 256, 0, stream>>>(S, Vt, out, Part, Flags);
}

// Round 7
// 257.384 us; speedup vs baseline: 1.4846x; 1.4846x over previous
//
#include <hip/hip_runtime.h>
#include <cstdint>
#include <cmath>

typedef unsigned short u16;
typedef u16   u16x4  __attribute__((ext_vector_type(4)));
typedef u16   u16x8  __attribute__((ext_vector_type(8)));
typedef __bf16 bf16x8 __attribute__((ext_vector_type(8)));
typedef float f32x4  __attribute__((ext_vector_type(4)));

__device__ __forceinline__ u16 f2bf(float f) {
    uint32_t u = __builtin_bit_cast(uint32_t, f);
    u += 0x7fffu + ((u >> 16) & 1u);   // round-to-nearest-even
    return (u16)(u >> 16);
}
__device__ __forceinline__ float bf2f(u16 v) {
    uint32_t u = ((uint32_t)v) << 16;
    return __builtin_bit_cast(float, u);
}
// async global->LDS, 16B per lane. LDS dest is wave-uniform base + lane*16.
__device__ __forceinline__ void gload_lds16(const u16* g, u16* l) {
    __builtin_amdgcn_global_load_lds((const __attribute__((address_space(1))) void*)g,
                                     (__attribute__((address_space(3))) void*)l,
                                     16, 0, 0);
}

// ---- prep: cast X fp32->bf16  +  transpose-cast W -> Wt[N][K] bf16 ----
__global__ __launch_bounds__(256) void prep_kernel(const float* __restrict__ X,
                                                   const float* __restrict__ Wq,
                                                   const float* __restrict__ Wk,
                                                   const float* __restrict__ Wv,
                                                   u16* __restrict__ Xb,
                                                   u16* __restrict__ Wt) {
    __shared__ u16 tile[64 * 72];
    typedef float f4 __attribute__((ext_vector_type(4)));
    const int bid = blockIdx.x;
    if (bid < 8192) {                       // cast X: 8192 blocks * 256 thr * 4 elems
        const int idx = bid * 256 + threadIdx.x;
        f4 f = ((const f4*)X)[idx];
        u16x4 o;
        o[0] = f2bf(f[0]); o[1] = f2bf(f[1]); o[2] = f2bf(f[2]); o[3] = f2bf(f[3]);
        ((u16x4*)Xb)[idx] = o;
        return;
    }
    const int id = bid - 8192;              // 768 blocks: W transpose-cast
    const int z = id >> 8, rem = id & 255;
    const float* W = (z == 0) ? Wq : (z == 1) ? Wk : Wv;
    u16* out = Wt + ((size_t)z << 20);
    const int nt = (rem & 15) * 64, kt = (rem >> 4) * 64;
    const int t = threadIdx.x, r = t >> 2, cq = (t & 3) * 16;
    const float* src = W + (size_t)(kt + r) * 1024 + nt + cq;
#pragma unroll
    for (int q = 0; q < 4; q++) {
        f4 f = ((const f4*)src)[q];
        tile[r * 72 + cq + q * 4 + 0] = f2bf(f[0]);
        tile[r * 72 + cq + q * 4 + 1] = f2bf(f[1]);
        tile[r * 72 + cq + q * 4 + 2] = f2bf(f[2]);
        tile[r * 72 + cq + q * 4 + 3] = f2bf(f[3]);
    }
    __syncthreads();
    u16x8 o0, o1;
#pragma unroll
    for (int e = 0; e < 8; e++) { o0[e] = tile[(cq + e) * 72 + r]; o1[e] = tile[(cq + 8 + e) * 72 + r]; }
    u16* dst = out + (size_t)(nt + r) * 1024 + kt + cq;
    *(u16x8*)dst = o0;
    *(u16x8*)(dst + 8) = o1;
}

// ------------- shared GEMM core: C[M,N] (+)= A[M,K_rng] * Bt[N,K_rng]^T -------------
// 128x128 tile, BK=32, 256 threads = 4 waves (2x2), 4x4 16x16x32 MFMA tiles/wave.
// LDS K-chunk XOR swizzle: LDS[row][c] holds global chunk c ^ ((row>>1)&3), applied by
// permuting each staging lane's GLOBAL address (LDS side of global_load_lds must stay
// lane-contiguous). Fragment reads XOR the same bits back. Fixes the measured ~8-way
// bank aliasing of row-stride-64B ds_read_b128 (R1: 6.3M conflict-cycles on qkv).
// OUTMODE: 0 = bf16 store, 1 = f32 store. Output origin (om0,on0) decoupled from input.
template <int OUTMODE>
__device__ __forceinline__ void gemm_bt_core(u16* __restrict__ smem,
                                             const u16* __restrict__ A,
                                             const u16* __restrict__ Bt,
                                             void* __restrict__ outp,
                                             const int ldk, const int ldo,
                                             const int kbeg, const int kend,
                                             const int m0, const int n0,
                                             const int om0, const int on0) {
    u16* As = smem;            // [128][32]
    u16* Bs = smem + 4096;     // [128][32]
    const int tid = (int)threadIdx.x;
    const int wave = tid >> 6, lane = tid & 63;
    const int wm = wave >> 1, wn = wave & 1;

    f32x4 acc[4][4] = {};

    const int sr = lane >> 2;                                  // staging row in 16-row group
    const int scw = ((lane & 3) ^ ((sr >> 1) & 3)) * 8;        // XOR-swizzled global col chunk
    const u16* gA = A  + (size_t)(m0 + wave * 32 + sr) * ldk + scw;
    const u16* gB = Bt + (size_t)(n0 + wave * 32 + sr) * ldk + scw;
    u16* lA = As + wave * 1024;          // wave-uniform LDS base
    u16* lB = Bs + wave * 1024;
    const size_t rstep = (size_t)ldk * 16;   // +16 rows: swizzle bits unchanged ((r+16)>>1 ≡ r>>1 mod 4)

    const int arow = lane & 15;
    const int ksw  = (arow >> 1) & 3;                          // same swizzle bits on read side
    const int koff = (((lane >> 4) ^ ksw)) * 8;
    const u16* pa = As + (wm * 64 + arow) * 32 + koff;
    const u16* pb = Bs + (wn * 64 + arow) * 32 + koff;

    for (int k0 = kbeg; k0 < kend; k0 += 32) {
        gload_lds16(gA + k0,         lA);
        gload_lds16(gA + k0 + rstep, lA + 512);
        gload_lds16(gB + k0,         lB);
        gload_lds16(gB + k0 + rstep, lB + 512);
        __syncthreads();
        bf16x8 a[4], b[4];
#pragma unroll
        for (int i = 0; i < 4; i++) a[i] = *(const bf16x8*)(pa + i * 512);
#pragma unroll
        for (int j = 0; j < 4; j++) b[j] = *(const bf16x8*)(pb + j * 512);
#pragma unroll
        for (int i = 0; i < 4; i++)
#pragma unroll
            for (int j = 0; j < 4; j++)
                acc[i][j] = __builtin_amdgcn_mfma_f32_16x16x32_bf16(a[i], b[j], acc[i][j], 0, 0, 0);
        __syncthreads();
    }

    // epilogue: C/D layout col=lane&15, row=(lane>>4)*4+reg  [m89/m91-verified]
    const int row0 = om0 + wm * 64 + ((lane >> 4) << 2);
    const int col0 = on0 + wn * 64 + (lane & 15);
    if constexpr (OUTMODE == 0) {
        u16* o = (u16*)outp;
#pragma unroll
        for (int i = 0; i < 4; i++)
#pragma unroll
            for (int r = 0; r < 4; r++) {
                u16* po = o + (size_t)(row0 + i * 16 + r) * ldo + col0;
#pragma unroll
                for (int j = 0; j < 4; j++) po[j * 16] = f2bf(acc[i][j][r]);
            }
    } else {
        float* o = (float*)outp;
#pragma unroll
        for (int i = 0; i < 4; i++)
#pragma unroll
            for (int r = 0; r < 4; r++) {
                float* po = o + (size_t)(row0 + i * 16 + r) * ldo + col0;
#pragma unroll
                for (int j = 0; j < 4; j++) po[j * 16] = acc[i][j][r];
            }
    }
}

// QKV: X[8192,1024] * Wt[z][1024,1024]^T -> QKV[z][8192,1024] bf16 (fused z-grid)
__global__ __launch_bounds__(256) void qkv_gemm_kernel(const u16* __restrict__ Xb,
                                                       const u16* __restrict__ Wt,
                                                       u16* __restrict__ QKV) {
    __shared__ u16 smem[8192];
    const int z = blockIdx.z;
    gemm_bt_core<0>(smem, Xb, Wt + ((size_t)z << 20), QKV + ((size_t)z << 23),
                    1024, 1024, 0, 1024, blockIdx.y * 128, blockIdx.x * 128,
                    blockIdx.y * 128, blockIdx.x * 128);
}

// fused: S = Q*K^T (544 causal tiles, compact triangular grid)  +  V transpose (2048 blocks).
__global__ __launch_bounds__(256) void s_tr_kernel(const u16* __restrict__ QKV,
                                                   u16* __restrict__ S,
                                                   u16* __restrict__ Vt) {
    __shared__ u16 smem[8192];
    const int bid = blockIdx.x;
    if (bid < 544) {
        const int b = bid / 136, t = bid - b * 136;
        int it = (int)((sqrtf(8.f * (float)t + 1.f) - 1.f) * 0.5f);
        while ((it + 1) * (it + 2) / 2 <= t) it++;
        while (it * (it + 1) / 2 > t) it--;
        const int jt = t - it * (it + 1) / 2;
        const u16* Q  = QKV + ((size_t)b << 21);
        const u16* Kp = QKV + ((size_t)1 << 23) + ((size_t)b << 21);
        gemm_bt_core<0>(smem, Q, Kp, S + ((size_t)b << 22), 1024, 2048, 0, 1024,
                        it * 128, jt * 128, it * 128, jt * 128);
        return;
    }
    // V[b][s][e] -> Vt[b][e][s], 64x64 tiles
    const int id = bid - 544;
    const int z = id >> 9, rem = id & 511;
    const u16* src = QKV + ((size_t)2 << 23) + ((size_t)z << 21);
    u16* dst = Vt + ((size_t)z << 21);
    const int st = (rem & 31) * 64, et = (rem >> 5) * 64;
    u16 (*tile)[72] = (u16(*)[72])smem;
    const int t = threadIdx.x, r = t >> 2, cq = (t & 3) * 16;
    const u16* p = src + (size_t)(st + r) * 1024 + et + cq;
    u16x8 u0 = *(const u16x8*)p;
    u16x8 u1 = *(const u16x8*)(p + 8);
#pragma unroll
    for (int e = 0; e < 8; e++) { tile[r][cq + e] = u0[e]; tile[r][cq + 8 + e] = u1[e]; }
    __syncthreads();
    u16x8 o0, o1;
#pragma unroll
    for (int e = 0; e < 8; e++) { o0[e] = tile[cq + e][r]; o1[e] = tile[cq + 8 + e][r]; }
    u16* q = dst + (size_t)(et + r) * 2048 + st + cq;
    *(u16x8*)q = o0;
    *(u16x8*)(q + 8) = o1;
}

// O = P * Vt^T. Deterministic 2-way split-K: tiles it>=8 split into c0 (direct f32
// store to O) and c1 (f32 partial into dead-Q buffer, reduced by reduce_kernel);
// it<8 whole. Slot table: CU-triples {c,c+256,c+512} sum to 17 K128-units each.
// NOTE (R6 lesson): do NOT merge partials in-kernel via __threadfence/look-back —
// device-scope fences in the epilogue forced L2 writebacks and cost +105 µs.
__global__ __launch_bounds__(256) void pv_gemm_kernel(const u16* __restrict__ P,
                                                      const u16* __restrict__ Vt,
                                                      float* __restrict__ O,
                                                      float* __restrict__ Part) {
    __shared__ u16 smem[8192];
    // slot -> (it, kind): kind 0=whole, 1=c0 [0,h), 2=c1 [h,u)
    const unsigned char IT[24]   = {15,14, 7,14,13,13,12,12, 15, 6,11,11,10,10, 9, 5,  0, 1, 2, 8, 3, 9, 8, 4};
    const unsigned char KIND[24] = { 1, 1, 0, 2, 1, 2, 1, 2,  2, 0, 1, 2, 1, 2, 1, 0,  0, 0, 0, 2, 0, 2, 1, 0};
    const int j = blockIdx.x;                 // 0..767
    const int slot = j >> 5, combo = j & 31;
    const int it = IT[slot], kind = KIND[slot];
    const int b = combo >> 3, n0 = (combo & 7) * 128;
    const int u = it + 1, h = (u + 1) >> 1;
    const int k_lo = (kind == 2) ? h * 128 : 0;
    const int k_hi = (kind == 1) ? h * 128 : u * 128;
    if (kind == 2) {
        float* dst = Part + ((size_t)((it - 8) * 32 + combo) << 14);   // 128x128 tile
        gemm_bt_core<1>(smem, P + ((size_t)b << 22), Vt + ((size_t)b << 21), dst,
                        2048, 128, k_lo, k_hi, it * 128, n0, 0, 0);
    } else {
        gemm_bt_core<1>(smem, P + ((size_t)b << 22), Vt + ((size_t)b << 21),
                        O + ((size_t)b << 21),
                        2048, 1024, k_lo, k_hi, it * 128, n0, it * 128, n0);
    }
}

// add split-K partials into O: 1024 blocks (4/CU), each a 32x128 quarter-tile.
// (R5's 256-block version was ~16 us of exposed latency at 1 block/CU.)
__global__ __launch_bounds__(256) void reduce_kernel(float* __restrict__ O,
                                                     const float* __restrict__ Part) {
    const int t = blockIdx.x;                 // 0..1023
    const int tile = t >> 2, q = t & 3;
    const int it = 8 + (tile >> 5), combo = tile & 31;
    const int b = combo >> 3, n0 = (combo & 7) * 128;
    const f32x4* p = (const f32x4*)(Part + ((size_t)tile << 14)) + q * 1024;
    float* o = O + ((size_t)b << 21) + (size_t)(it * 128 + q * 32) * 1024 + n0;
    const int tid = threadIdx.x;
#pragma unroll
    for (int e = 0; e < 4; e++) {
        const int flat = e * 256 + tid;       // f32x4 index within 32x128 quarter
        const int row = flat >> 5, col = (flat & 31) * 4;
        f32x4 pv = p[flat];
        f32x4* po = (f32x4*)(o + (size_t)row * 1024 + col);
        f32x4 ov = *po;
        ov[0] += pv[0]; ov[1] += pv[1]; ov[2] += pv[2]; ov[3] += pv[3];
        *po = ov;
    }
}

// --------- in-place causal softmax (scale 1/32), truncated to kend=((i>>7)+1)*128 ---------
__global__ __launch_bounds__(256) void softmax_kernel(u16* __restrict__ S) {
    const int wave = threadIdx.x >> 6, lane = threadIdx.x & 63;
    const int g = blockIdx.x * 4 + wave;       // 0..8191
    const int b = g >> 11, i = g & 2047;
    u16* row = S + ((size_t)b << 22) + ((size_t)i << 11);
    const int n = i + 1;                        // valid keys
    const int kend = ((i >> 7) + 1) << 7;       // pv reads cols [0, kend)
    const int nt_ = (kend + 511) >> 9;          // active 512-col chunks (1..4), wave-uniform
    const float NEG = -1e30f;
    float v[32];
    float m = NEG;
#pragma unroll
    for (int t = 0; t < 4; t++) {
        if (t < nt_) {
            u16x8 u = *(const u16x8*)(row + t * 512 + lane * 8);
#pragma unroll
            for (int e = 0; e < 8; e++) {
                const int col = t * 512 + lane * 8 + e;
                float f = (col < n) ? bf2f(u[e]) : NEG;
                v[t * 8 + e] = f;
                m = fmaxf(m, f);
            }
        }
    }
#pragma unroll
    for (int off = 32; off > 0; off >>= 1) m = fmaxf(m, __shfl_xor(m, off, 64));
    const float sc = 0.03125f * 1.44269504088896f;   // (1/sqrt(1024)) * log2(e)
    float s = 0.f;
#pragma unroll
    for (int t = 0; t < 4; t++) {
        if (t < nt_) {
#pragma unroll
            for (int e = 0; e < 8; e++) {
                const float x = v[t * 8 + e];
                const float e2 = (x == NEG) ? 0.f : exp2f((x - m) * sc);
                v[t * 8 + e] = e2;
                s += e2;
            }
        }
    }
#pragma unroll
    for (int off = 32; off > 0; off >>= 1) s += __shfl_xor(s, off, 64);
    const float inv = 1.f / s;
#pragma unroll
    for (int t = 0; t < 4; t++) {
        if (t < nt_) {
            u16x8 o;
#pragma unroll
            for (int e = 0; e < 8; e++) o[e] = f2bf(v[t * 8 + e] * inv);
            *(u16x8*)(row + t * 512 + lane * 8) = o;
        }
    }
}

extern "C" void kernel_launch(void* const* d_in, const int* in_sizes, int n_in,
                              void* d_out, int out_size, void* d_ws, size_t ws_size,
                              hipStream_t stream) {
    const float* X  = (const float*)d_in[0];
    const float* Wq = (const float*)d_in[1];
    const float* Wk = (const float*)d_in[2];
    const float* Wv = (const float*)d_in[3];
    float* out = (float*)d_out;

    // ws layout (u16 elems): Xb 8M | Wt 3M | QKV 24M | S 16M  -> ~102 MB
    u16* ws  = (u16*)d_ws;
    u16* Xb  = ws;                                   // 1<<23 elems (reused as Vt)
    u16* Wt  = Xb + ((size_t)1 << 23);               // 3 * (1<<20)
    u16* QKV = Wt + 3 * ((size_t)1 << 20);           // 3 * (1<<23)
    u16* S   = QKV + 3 * ((size_t)1 << 23);          // 1<<24
    u16* Vt  = Xb;                                   // Xb dead after QKV GEMM
    float* Part = (float*)QKV;                       // Q region (16 MB) dead during pv

    prep_kernel<<<8960, 256, 0, stream>>>(X, Wq, Wk, Wv, Xb, Wt);
    qkv_gemm_kernel<<<dim3(8, 64, 3), 256, 0, stream>>>(Xb, Wt, QKV);
    s_tr_kernel<<<2592, 256, 0, stream>>>(QKV, S, Vt);
    softmax_kernel<<<2048, 256, 0, stream>>>(S);
    pv_gemm_kernel<<<768, 256, 0, stream>>>(S, Vt, out, Part);
    reduce_kernel<<<1024, 256, 0, stream>>>(out, Part);
}

// Round 8
// 239.880 us; speedup vs baseline: 1.5929x; 1.0730x over previous
//
#include <hip/hip_runtime.h>
#include <cstdint>
#include <cmath>

typedef unsigned short u16;
typedef u16   u16x4  __attribute__((ext_vector_type(4)));
typedef u16   u16x8  __attribute__((ext_vector_type(8)));
typedef __bf16 bf16x8 __attribute__((ext_vector_type(8)));
typedef float f32x4  __attribute__((ext_vector_type(4)));

__device__ __forceinline__ u16 f2bf(float f) {
    uint32_t u = __builtin_bit_cast(uint32_t, f);
    u += 0x7fffu + ((u >> 16) & 1u);   // round-to-nearest-even
    return (u16)(u >> 16);
}
__device__ __forceinline__ float bf2f(u16 v) {
    uint32_t u = ((uint32_t)v) << 16;
    return __builtin_bit_cast(float, u);
}
// async global->LDS, 16B per lane. LDS dest is wave-uniform base + lane*16.
__device__ __forceinline__ void gload_lds16(const u16* g, u16* l) {
    __builtin_amdgcn_global_load_lds((const __attribute__((address_space(1))) void*)g,
                                     (__attribute__((address_space(3))) void*)l,
                                     16, 0, 0);
}

// ---- prep: cast X fp32->bf16  +  transpose-cast W -> Wt[N][K] bf16 ----
__global__ __launch_bounds__(256) void prep_kernel(const float* __restrict__ X,
                                                   const float* __restrict__ Wq,
                                                   const float* __restrict__ Wk,
                                                   const float* __restrict__ Wv,
                                                   u16* __restrict__ Xb,
                                                   u16* __restrict__ Wt) {
    __shared__ u16 tile[64 * 72];
    typedef float f4 __attribute__((ext_vector_type(4)));
    const int bid = blockIdx.x;
    if (bid < 8192) {                       // cast X: 8192 blocks * 256 thr * 4 elems
        const int idx = bid * 256 + threadIdx.x;
        f4 f = ((const f4*)X)[idx];
        u16x4 o;
        o[0] = f2bf(f[0]); o[1] = f2bf(f[1]); o[2] = f2bf(f[2]); o[3] = f2bf(f[3]);
        ((u16x4*)Xb)[idx] = o;
        return;
    }
    const int id = bid - 8192;              // 768 blocks: W transpose-cast
    const int z = id >> 8, rem = id & 255;
    const float* W = (z == 0) ? Wq : (z == 1) ? Wk : Wv;
    u16* out = Wt + ((size_t)z << 20);
    const int nt = (rem & 15) * 64, kt = (rem >> 4) * 64;
    const int t = threadIdx.x, r = t >> 2, cq = (t & 3) * 16;
    const float* src = W + (size_t)(kt + r) * 1024 + nt + cq;
#pragma unroll
    for (int q = 0; q < 4; q++) {
        f4 f = ((const f4*)src)[q];
        tile[r * 72 + cq + q * 4 + 0] = f2bf(f[0]);
        tile[r * 72 + cq + q * 4 + 1] = f2bf(f[1]);
        tile[r * 72 + cq + q * 4 + 2] = f2bf(f[2]);
        tile[r * 72 + cq + q * 4 + 3] = f2bf(f[3]);
    }
    __syncthreads();
    u16x8 o0, o1;
#pragma unroll
    for (int e = 0; e < 8; e++) { o0[e] = tile[(cq + e) * 72 + r]; o1[e] = tile[(cq + 8 + e) * 72 + r]; }
    u16* dst = out + (size_t)(nt + r) * 1024 + kt + cq;
    *(u16x8*)dst = o0;
    *(u16x8*)(dst + 8) = o1;
}

// ------------- shared GEMM core: C[M,N] (+)= A[M,K_rng] * Bt[N,K_rng]^T -------------
// 128x128 tile, BK=32, 256 threads = 4 waves (2x2), 4x4 16x16x32 MFMA tiles/wave.
// LDS K-chunk XOR swizzle (R7: verified SQ_LDS_BANK_CONFLICT 6.3M -> 0).
// OUTMODE: 0 = bf16 store, 1 = f32 store. Output origin (om0,on0) decoupled from input.
template <int OUTMODE>
__device__ __forceinline__ void gemm_bt_core(u16* __restrict__ smem,
                                             const u16* __restrict__ A,
                                             const u16* __restrict__ Bt,
                                             void* __restrict__ outp,
                                             const int ldk, const int ldo,
                                             const int kbeg, const int kend,
                                             const int m0, const int n0,
                                             const int om0, const int on0) {
    u16* As = smem;            // [128][32]
    u16* Bs = smem + 4096;     // [128][32]
    const int tid = (int)threadIdx.x;
    const int wave = tid >> 6, lane = tid & 63;
    const int wm = wave >> 1, wn = wave & 1;

    f32x4 acc[4][4] = {};

    const int sr = lane >> 2;                                  // staging row in 16-row group
    const int scw = ((lane & 3) ^ ((sr >> 1) & 3)) * 8;        // XOR-swizzled global col chunk
    const u16* gA = A  + (size_t)(m0 + wave * 32 + sr) * ldk + scw;
    const u16* gB = Bt + (size_t)(n0 + wave * 32 + sr) * ldk + scw;
    u16* lA = As + wave * 1024;          // wave-uniform LDS base
    u16* lB = Bs + wave * 1024;
    const size_t rstep = (size_t)ldk * 16;   // +16 rows: swizzle bits unchanged

    const int arow = lane & 15;
    const int ksw  = (arow >> 1) & 3;                          // same swizzle bits on read side
    const int koff = (((lane >> 4) ^ ksw)) * 8;
    const u16* pa = As + (wm * 64 + arow) * 32 + koff;
    const u16* pb = Bs + (wn * 64 + arow) * 32 + koff;

    for (int k0 = kbeg; k0 < kend; k0 += 32) {
        gload_lds16(gA + k0,         lA);
        gload_lds16(gA + k0 + rstep, lA + 512);
        gload_lds16(gB + k0,         lB);
        gload_lds16(gB + k0 + rstep, lB + 512);
        __syncthreads();
        bf16x8 a[4], b[4];
#pragma unroll
        for (int i = 0; i < 4; i++) a[i] = *(const bf16x8*)(pa + i * 512);
#pragma unroll
        for (int j = 0; j < 4; j++) b[j] = *(const bf16x8*)(pb + j * 512);
#pragma unroll
        for (int i = 0; i < 4; i++)
#pragma unroll
            for (int j = 0; j < 4; j++)
                acc[i][j] = __builtin_amdgcn_mfma_f32_16x16x32_bf16(a[i], b[j], acc[i][j], 0, 0, 0);
        __syncthreads();
    }

    // epilogue: C/D layout col=lane&15, row=(lane>>4)*4+reg  [m89/m91-verified]
    const int row0 = om0 + wm * 64 + ((lane >> 4) << 2);
    const int col0 = on0 + wn * 64 + (lane & 15);
    if constexpr (OUTMODE == 0) {
        u16* o = (u16*)outp;
#pragma unroll
        for (int i = 0; i < 4; i++)
#pragma unroll
            for (int r = 0; r < 4; r++) {
                u16* po = o + (size_t)(row0 + i * 16 + r) * ldo + col0;
#pragma unroll
                for (int j = 0; j < 4; j++) po[j * 16] = f2bf(acc[i][j][r]);
            }
    } else {
        float* o = (float*)outp;
#pragma unroll
        for (int i = 0; i < 4; i++)
#pragma unroll
            for (int r = 0; r < 4; r++) {
                float* po = o + (size_t)(row0 + i * 16 + r) * ldo + col0;
#pragma unroll
                for (int j = 0; j < 4; j++) po[j * 16] = acc[i][j][r];
            }
    }
}

// QKV: X[8192,1024] * Wt[z][1024,1024]^T -> QKV[z][8192,1024] bf16.
// XCD-banded swizzle: XCD (bid%8) owns y-band y=xcd*8+yl (2 MB of Xb, fits its
// 4 MB L2), z-outer so live set ~= A-band + one Wt. Fixes R7's 136 MB (6x) L2
// over-fetch from the column-sliced default mapping.
__global__ __launch_bounds__(256) void qkv_gemm_kernel(const u16* __restrict__ Xb,
                                                       const u16* __restrict__ Wt,
                                                       u16* __restrict__ QKV) {
    __shared__ u16 smem[8192];
    const int bid = blockIdx.x;               // 0..1535
    const int xcd = bid & 7, slot = bid >> 3; // 192 slots per XCD
    const int z = slot >> 6;                  // z outer: 64 slots per z
    const int rem = slot & 63;
    const int yl = rem >> 3, x = rem & 7;
    const int y = (xcd << 3) | yl;            // y-band per XCD
    gemm_bt_core<0>(smem, Xb, Wt + ((size_t)z << 20), QKV + ((size_t)z << 23),
                    1024, 1024, 0, 1024, y * 128, x * 128, y * 128, x * 128);
}

// fused: S = Q*K^T (causal tiles, XCD-banded)  +  V transpose (2048 blocks).
// GEMM tiles banded: XCD = (b<<1)|half; half 0 = it 0..10 (66 tiles), half 1 =
// it 11..15 (70 tiles); 72 slots each (few idle). Working set ~5.5 MB/XCD vs
// the old full-scatter ~8 MB/batch across all XCDs (R5 FETCH 110 MB).
__global__ __launch_bounds__(256) void s_tr_kernel(const u16* __restrict__ QKV,
                                                   u16* __restrict__ S,
                                                   u16* __restrict__ Vt) {
    __shared__ u16 smem[8192];
    const int bid = blockIdx.x;
    if (bid < 576) {
        const int xcd = bid & 7, slot = bid >> 3;   // slot 0..71
        const int b = xcd >> 1, half = xcd & 1;
        int it = half ? 11 : 0;
        const int ntiles = half ? 70 : 66;
        if (slot >= ntiles) return;
        int acc = 0;
        while (acc + it + 1 <= slot) { acc += it + 1; it++; }
        const int jt = slot - acc;
        const u16* Q  = QKV + ((size_t)b << 21);
        const u16* Kp = QKV + ((size_t)1 << 23) + ((size_t)b << 21);
        gemm_bt_core<0>(smem, Q, Kp, S + ((size_t)b << 22), 1024, 2048, 0, 1024,
                        it * 128, jt * 128, it * 128, jt * 128);
        return;
    }
    // V[b][s][e] -> Vt[b][e][s], 64x64 tiles
    const int id = bid - 576;
    const int z = id >> 9, rem = id & 511;
    const u16* src = QKV + ((size_t)2 << 23) + ((size_t)z << 21);
    u16* dst = Vt + ((size_t)z << 21);
    const int st = (rem & 31) * 64, et = (rem >> 5) * 64;
    u16 (*tile)[72] = (u16(*)[72])smem;
    const int t = threadIdx.x, r = t >> 2, cq = (t & 3) * 16;
    const u16* p = src + (size_t)(st + r) * 1024 + et + cq;
    u16x8 u0 = *(const u16x8*)p;
    u16x8 u1 = *(const u16x8*)(p + 8);
#pragma unroll
    for (int e = 0; e < 8; e++) { tile[r][cq + e] = u0[e]; tile[r][cq + 8 + e] = u1[e]; }
    __syncthreads();
    u16x8 o0, o1;
#pragma unroll
    for (int e = 0; e < 8; e++) { o0[e] = tile[cq + e][r]; o1[e] = tile[cq + 8 + e][r]; }
    u16* q = dst + (size_t)(et + r) * 2048 + st + cq;
    *(u16x8*)q = o0;
    *(u16x8*)(q + 8) = o1;
}

// O = P * Vt^T. Deterministic 2-way split-K: tiles it>=8 split into c0 (direct f32
// store to O) and c1 (f32 partial into dead-Q buffer, reduced by reduce_kernel);
// it<8 whole. Slot table: CU-triples {c,c+256,c+512} sum to 17 K128-units each.
// NOTE (R6 lesson): no __threadfence look-back merge — cost +105 us.
__global__ __launch_bounds__(256) void pv_gemm_kernel(const u16* __restrict__ P,
                                                      const u16* __restrict__ Vt,
                                                      float* __restrict__ O,
                                                      float* __restrict__ Part) {
    __shared__ u16 smem[8192];
    // slot -> (it, kind): kind 0=whole, 1=c0 [0,h), 2=c1 [h,u)
    const unsigned char IT[24]   = {15,14, 7,14,13,13,12,12, 15, 6,11,11,10,10, 9, 5,  0, 1, 2, 8, 3, 9, 8, 4};
    const unsigned char KIND[24] = { 1, 1, 0, 2, 1, 2, 1, 2,  2, 0, 1, 2, 1, 2, 1, 0,  0, 0, 0, 2, 0, 2, 1, 0};
    const int j = blockIdx.x;                 // 0..767
    const int slot = j >> 5, combo = j & 31;
    const int it = IT[slot], kind = KIND[slot];
    const int b = combo >> 3, n0 = (combo & 7) * 128;
    const int u = it + 1, h = (u + 1) >> 1;
    const int k_lo = (kind == 2) ? h * 128 : 0;
    const int k_hi = (kind == 1) ? h * 128 : u * 128;
    if (kind == 2) {
        float* dst = Part + ((size_t)((it - 8) * 32 + combo) << 14);   // 128x128 tile
        gemm_bt_core<1>(smem, P + ((size_t)b << 22), Vt + ((size_t)b << 21), dst,
                        2048, 128, k_lo, k_hi, it * 128, n0, 0, 0);
    } else {
        gemm_bt_core<1>(smem, P + ((size_t)b << 22), Vt + ((size_t)b << 21),
                        O + ((size_t)b << 21),
                        2048, 1024, k_lo, k_hi, it * 128, n0, it * 128, n0);
    }
}

// add split-K partials into O: 1024 blocks (4/CU), each a 32x128 quarter-tile.
__global__ __launch_bounds__(256) void reduce_kernel(float* __restrict__ O,
                                                     const float* __restrict__ Part) {
    const int t = blockIdx.x;                 // 0..1023
    const int tile = t >> 2, q = t & 3;
    const int it = 8 + (tile >> 5), combo = tile & 31;
    const int b = combo >> 3, n0 = (combo & 7) * 128;
    const f32x4* p = (const f32x4*)(Part + ((size_t)tile << 14)) + q * 1024;
    float* o = O + ((size_t)b << 21) + (size_t)(it * 128 + q * 32) * 1024 + n0;
    const int tid = threadIdx.x;
#pragma unroll
    for (int e = 0; e < 4; e++) {
        const int flat = e * 256 + tid;       // f32x4 index within 32x128 quarter
        const int row = flat >> 5, col = (flat & 31) * 4;
        f32x4 pv = p[flat];
        f32x4* po = (f32x4*)(o + (size_t)row * 1024 + col);
        f32x4 ov = *po;
        ov[0] += pv[0]; ov[1] += pv[1]; ov[2] += pv[2]; ov[3] += pv[3];
        *po = ov;
    }
}

// --------- in-place causal softmax (scale 1/32), truncated to kend=((i>>7)+1)*128 ---------
__global__ __launch_bounds__(256) void softmax_kernel(u16* __restrict__ S) {
    const int wave = threadIdx.x >> 6, lane = threadIdx.x & 63;
    const int g = blockIdx.x * 4 + wave;       // 0..8191
    const int b = g >> 11, i = g & 2047;
    u16* row = S + ((size_t)b << 22) + ((size_t)i << 11);
    const int n = i + 1;                        // valid keys
    const int kend = ((i >> 7) + 1) << 7;       // pv reads cols [0, kend)
    const int nt_ = (kend + 511) >> 9;          // active 512-col chunks (1..4), wave-uniform
    const float NEG = -1e30f;
    float v[32];
    float m = NEG;
#pragma unroll
    for (int t = 0; t < 4; t++) {
        if (t < nt_) {
            u16x8 u = *(const u16x8*)(row + t * 512 + lane * 8);
#pragma unroll
            for (int e = 0; e < 8; e++) {
                const int col = t * 512 + lane * 8 + e;
                float f = (col < n) ? bf2f(u[e]) : NEG;
                v[t * 8 + e] = f;
                m = fmaxf(m, f);
            }
        }
    }
#pragma unroll
    for (int off = 32; off > 0; off >>= 1) m = fmaxf(m, __shfl_xor(m, off, 64));
    const float sc = 0.03125f * 1.44269504088896f;   // (1/sqrt(1024)) * log2(e)
    float s = 0.f;
#pragma unroll
    for (int t = 0; t < 4; t++) {
        if (t < nt_) {
#pragma unroll
            for (int e = 0; e < 8; e++) {
                const float x = v[t * 8 + e];
                const float e2 = (x == NEG) ? 0.f : exp2f((x - m) * sc);
                v[t * 8 + e] = e2;
                s += e2;
            }
        }
    }
#pragma unroll
    for (int off = 32; off > 0; off >>= 1) s += __shfl_xor(s, off, 64);
    const float inv = 1.f / s;
#pragma unroll
    for (int t = 0; t < 4; t++) {
        if (t < nt_) {
            u16x8 o;
#pragma unroll
            for (int e = 0; e < 8; e++) o[e] = f2bf(v[t * 8 + e] * inv);
            *(u16x8*)(row + t * 512 + lane * 8) = o;
        }
    }
}

extern "C" void kernel_launch(void* const* d_in, const int* in_sizes, int n_in,
                              void* d_out, int out_size, void* d_ws, size_t ws_size,
                              hipStream_t stream) {
    const float* X  = (const float*)d_in[0];
    const float* Wq = (const float*)d_in[1];
    const float* Wk = (const float*)d_in[2];
    const float* Wv = (const float*)d_in[3];
    float* out = (float*)d_out;

    // ws layout (u16 elems): Xb 8M | Wt 3M | QKV 24M | S 16M  -> ~102 MB
    u16* ws  = (u16*)d_ws;
    u16* Xb  = ws;                                   // 1<<23 elems (reused as Vt)
    u16* Wt  = Xb + ((size_t)1 << 23);               // 3 * (1<<20)
    u16* QKV = Wt + 3 * ((size_t)1 << 20);           // 3 * (1<<23)
    u16* S   = QKV + 3 * ((size_t)1 << 23);          // 1<<24
    u16* Vt  = Xb;                                   // Xb dead after QKV GEMM
    float* Part = (float*)QKV;                       // Q region (16 MB) dead during pv

    prep_kernel<<<8960, 256, 0, stream>>>(X, Wq, Wk, Wv, Xb, Wt);
    qkv_gemm_kernel<<<1536, 256, 0, stream>>>(Xb, Wt, QKV);
    s_tr_kernel<<<2624, 256, 0, stream>>>(QKV, S, Vt);
    softmax_kernel<<<2048, 256, 0, stream>>>(S);
    pv_gemm_kernel<<<768, 256, 0, stream>>>(S, Vt, out, Part);
    reduce_kernel<<<1024, 256, 0, stream>>>(out, Part);
}